// Round 6
// baseline (995.071 us; speedup 1.0000x reference)
//
#include <hip/hip_runtime.h>
#include <hip/hip_bf16.h>

typedef __bf16 bf16_t;
typedef __bf16 bf16x8 __attribute__((ext_vector_type(8)));
typedef float floatx4 __attribute__((ext_vector_type(4)));

#define D_MODEL 768
#define D_INNER 1536
#define D_STATE 16
#define DT_RANK 48
#define NROWS 2048   /* B*L */
#define LSEQ 1024
#define SCAN_C 32            /* chunks per sequence */
#define SCAN_RPC 32          /* rows per chunk = LSEQ/SCAN_C */
#define SCAN_NDG 24          /* d-groups of 64 = D_INNER/64 */
#define SCAN_STRIDE 24576    /* D_INNER*D_STATE floats per (b,chunk) */

// ---------------------------------------------------------------------------
// detect (only needed for the small-workspace fallback logits path).
// fp32 ln_w[0] -> 0x3F800000; bf16 pair -> 0x3F803F80.
// ---------------------------------------------------------------------------
__global__ void detect_kernel(const unsigned int* __restrict__ lnw, int* __restrict__ flag) {
  if (threadIdx.x == 0 && blockIdx.x == 0)
    *flag = (lnw[0] == 0x3F800000u) ? 0 : 1;
}

// ---------------------------------------------------------------------------
// fused_pre: ONE kernel for all preprocessing (was 5 dispatches):
//   S0: 11 weight tensors -> contiguous bf16 wk
//   S1: x_proj W pad (read from SOURCE tensor -> no intra-kernel dependency)
//   S2: embedding table -> bf16 (skipped when !bigws)
//   S3: embedding gather -> h (f32) + hb (bf16)
// dtype flag derived per-thread from ln_w[0] (uniform, L2-broadcast).
// ---------------------------------------------------------------------------
struct CvtSrcs { const void* p[11]; };

__global__ __launch_bounds__(256) void fused_pre(CvtSrcs sp,
                                                 const int* __restrict__ x,
                                                 const void* __restrict__ emb,
                                                 bf16_t* __restrict__ wk,
                                                 bf16_t* __restrict__ xpwp,
                                                 bf16_t* __restrict__ embb,
                                                 float* __restrict__ h,
                                                 bf16_t* __restrict__ hb,
                                                 int bigws) {
  const long N0 = 7543296, N1 = 393216, N2 = 3072000;
  long idx = (long)blockIdx.x * 256 + threadIdx.x;
  unsigned w0 = ((const unsigned int*)sp.p[9])[0];   // ln_w first word
  int isbf = (w0 != 0x3F800000u);

  if (idx < N0) {
    // ---- S0: weight canonicalize ----
    int i = (int)idx;
    const int off[12] = {0, 4718592, 4730880, 4733952, 4979712, 5127168, 5130240,
                         5179392, 5182464, 7541760, 7542528, 7543296};
    const void* src = sp.p[0];
    int base = 0;
#pragma unroll
    for (int k = 1; k <= 10; k++) {
      if (i >= off[k]) { src = sp.p[k]; base = off[k]; }
    }
    int j = i - base;
    float v = isbf ? (float)((const bf16_t*)src)[j] : ((const float*)src)[j];
    wk[i] = (bf16_t)v;
  } else if (idx < N0 + N1) {
    // ---- S1: x_proj W pad (2,80,1536) -> (2,128,1536) ----
    int i2 = (int)(idx - N0);
    int c = i2 % 1536;
    int r = (i2 / 1536) % 128;
    int lay = i2 / (128 * 1536);
    float v = 0.f;
    if (r < 80) {
      size_t so = ((size_t)lay * 80 + r) * 1536 + c;
      v = isbf ? (float)((const bf16_t*)sp.p[3])[so] : ((const float*)sp.p[3])[so];
    }
    xpwp[i2] = (bf16_t)v;
  } else if (idx < N0 + N1 + N2) {
    // ---- S2: embedding -> bf16 (8-elem chunks) ----
    if (!bigws) return;
    long i3 = idx - N0 - N1;
    if (isbf) {
      ((uint4*)embb)[i3] = ((const uint4*)emb)[i3];
    } else {
      const float4* s = (const float4*)emb + i3 * 2;
      float4 f0 = s[0], f1 = s[1];
      bf16x8 v;
      v[0] = (bf16_t)f0.x; v[1] = (bf16_t)f0.y; v[2] = (bf16_t)f0.z; v[3] = (bf16_t)f0.w;
      v[4] = (bf16_t)f1.x; v[5] = (bf16_t)f1.y; v[6] = (bf16_t)f1.z; v[7] = (bf16_t)f1.w;
      *(bf16x8*)(embb + i3 * 8) = v;
    }
  } else {
    // ---- S3: embedding gather ----
    int i4 = (int)(idx - N0 - N1 - N2);             // < 2048*768
    int row = i4 / D_MODEL, cc = i4 - row * D_MODEL;
    size_t o = (size_t)x[row] * D_MODEL + cc;
    float v = isbf ? (float)((const bf16_t*)emb)[o] : ((const float*)emb)[o];
    h[i4] = v;
    hb[i4] = (bf16_t)v;
  }
}

// ---------------------------------------------------------------------------
// MFMA GEMM: C(M,N) = A(M,K) * Bw(N,K)^T. A always bf16 (16B-aligned rows).
// K must be a multiple of 64. BK=64, linear LDS, global_load_lds dwordx4
// with XOR chunk swizzle (source+read sides; rule 21).
// mode 0: Cf = acc; mode 1: v=acc+res -> Cf,Cb; mode 2: Cf = acc (fp32 out)
// mode 3: Cf[row*80+col] = acc, only col<80  [x_proj into xdbl, stride 80]
// swapgrid 0: nb=bx, mb=by.  1: mb=bx, nb=by.
// swapgrid 2: XCD-chunked bijective remap (requires gridDim.x==16 and
//   nwg%8==0): all 16 sharers of a B panel sit on ONE XCD's L2.
// ---------------------------------------------------------------------------
typedef __attribute__((address_space(3))) void lds_void_t;
typedef __attribute__((address_space(1))) void glb_void_t;

__device__ __forceinline__ void gload16(const void* g, void* l) {
  __builtin_amdgcn_global_load_lds((const glb_void_t*)(unsigned long long)g,
                                   (lds_void_t*)(unsigned long long)l, 16, 0, 0);
}

__global__ __launch_bounds__(256) void gemm_bt(const bf16_t* __restrict__ A,
                                               const void* __restrict__ Bw,
                                               int M, int N, int K, int mode,
                                               float* __restrict__ Cf,
                                               bf16_t* __restrict__ Cb,
                                               const float* __restrict__ res,
                                               const int* __restrict__ flagp,
                                               int swapgrid) {
  __shared__ __align__(16) bf16_t As[128 * 64];
  __shared__ __align__(16) bf16_t Bs[128 * 64];
  int bNative = flagp ? (*flagp == 0) : 0;      // 1 -> Bw is fp32
  int tid = threadIdx.x;
  int mb, nb;
  if (swapgrid == 2) {
    int nwg = gridDim.x * gridDim.y;            // multiple of 8
    int lin = blockIdx.y * gridDim.x + blockIdx.x;
    int cpx = nwg >> 3;
    int nid = (lin & 7) * cpx + (lin >> 3);
    mb = nid & 15;                              // gridDim.x == 16
    nb = nid >> 4;
  } else if (swapgrid == 1) {
    mb = blockIdx.x; nb = blockIdx.y;
  } else {
    nb = blockIdx.x; mb = blockIdx.y;
  }
  int m0 = mb * 128, n0 = nb * 128;
  int wave = tid >> 6, lane = tid & 63;
  int wr = wave >> 1, wc = wave & 1;
  int m16 = lane & 15, ksel = lane >> 4;
  int srow = lane >> 3;                         // 0..7 within an 8-row slab
  int sseg = lane & 7;

  floatx4 acc[4][4];
#pragma unroll
  for (int i = 0; i < 4; i++)
#pragma unroll
    for (int j = 0; j < 4; j++) acc[i][j] = (floatx4){0.f, 0.f, 0.f, 0.f};

  for (int k0 = 0; k0 < K; k0 += 64) {
#pragma unroll
    for (int i = 0; i < 4; i++) {
      int j = wave * 4 + i;
      int row = j * 8 + srow;
      int sg = sseg ^ (row & 7);
      gload16(A + (size_t)(m0 + row) * K + k0 + sg * 8, &As[j * 512]);
    }
    if (!bNative) {
#pragma unroll
      for (int i = 0; i < 4; i++) {
        int j = wave * 4 + i;
        int row = j * 8 + srow;
        int sg = sseg ^ (row & 7);
        gload16((const bf16_t*)Bw + (size_t)(n0 + row) * K + k0 + sg * 8, &Bs[j * 512]);
      }
    } else {
#pragma unroll
      for (int rep = 0; rep < 4; rep++) {
        int l = tid + rep * 256;
        int row = l >> 3, sg = l & 7;
        const float* gb = (const float*)Bw + (size_t)(n0 + row) * K + k0 + sg * 8;
        float4 f0 = *(const float4*)gb;
        float4 f1 = *(const float4*)(gb + 4);
        bf16x8 v;
        v[0] = (bf16_t)f0.x; v[1] = (bf16_t)f0.y; v[2] = (bf16_t)f0.z; v[3] = (bf16_t)f0.w;
        v[4] = (bf16_t)f1.x; v[5] = (bf16_t)f1.y; v[6] = (bf16_t)f1.z; v[7] = (bf16_t)f1.w;
        *(bf16x8*)&Bs[row * 64 + (sg ^ (row & 7)) * 8] = v;
      }
    }
    __syncthreads();
#pragma unroll
    for (int kk = 0; kk < 2; kk++) {
      int ck = (ksel + 4 * kk) ^ (lane & 7);
      bf16x8 aF[4], bF[4];
#pragma unroll
      for (int mi = 0; mi < 4; mi++)
        aF[mi] = *(const bf16x8*)&As[(wr * 64 + mi * 16 + m16) * 64 + ck * 8];
#pragma unroll
      for (int ni = 0; ni < 4; ni++)
        bF[ni] = *(const bf16x8*)&Bs[(wc * 64 + ni * 16 + m16) * 64 + ck * 8];
#pragma unroll
      for (int mi = 0; mi < 4; mi++)
#pragma unroll
        for (int ni = 0; ni < 4; ni++)
          acc[mi][ni] = __builtin_amdgcn_mfma_f32_16x16x32_bf16(aF[mi], bF[ni], acc[mi][ni], 0, 0, 0);
    }
    __syncthreads();
  }

#pragma unroll
  for (int mi = 0; mi < 4; mi++)
#pragma unroll
    for (int ni = 0; ni < 4; ni++)
#pragma unroll
      for (int r = 0; r < 4; r++) {
        int row = m0 + wr * 64 + mi * 16 + ksel * 4 + r;
        int col = n0 + wc * 64 + ni * 16 + m16;
        size_t off = (size_t)row * N + col;
        float v = acc[mi][ni][r];
        if (mode == 0) {
          Cf[off] = v;
        } else if (mode == 1) {
          float o = v + res[off];
          Cf[off] = o;
          Cb[off] = (bf16_t)o;
        } else if (mode == 2) {
          Cf[off] = v;
        } else {                    // mode 3: xdbl, row stride 80, cols<80
          if (col < 80) Cf[(size_t)row * 80 + col] = v;
        }
      }
}

// ---------------------------------------------------------------------------
// Depthwise causal conv1d (K=4) + bias + SiLU. x_in = xz[:, 0:1536] (f32).
// ---------------------------------------------------------------------------
__global__ __launch_bounds__(256) void conv_silu(const float* __restrict__ xz,
                                                 const bf16_t* __restrict__ cw,
                                                 const bf16_t* __restrict__ cb,
                                                 bf16_t* __restrict__ xc) {
  int idx = blockIdx.x * 256 + threadIdx.x;   // NROWS*D_INNER
  if (idx >= NROWS * D_INNER) return;
  int d = idx % D_INNER;
  int row = idx / D_INNER;
  int l = row % LSEQ;
  int base = row - l;                         // start row of this batch
  float s = (float)cb[d];
#pragma unroll
  for (int k = 0; k < 4; k++) {
    int ll = l - 3 + k;
    if (ll >= 0) s += (float)cw[d * 4 + k] * xz[(size_t)(base + ll) * (2 * D_INNER) + d];
  }
  float sil = s / (1.f + __expf(-s));
  xc[idx] = (bf16_t)sil;
}

// ---------------------------------------------------------------------------
// Chunked selective scan (3 phases) with dt_proj FUSED into p1/p3:
// dt(r,d) = softplus(xdbl[r,0:48] . dtw[d,:] + dtb[d]) computed in-register
// (per-lane d is fixed -> the 48 dt-weights preload into 6 bf16x8 regs; the
// xdbl row is wave-uniform -> scalar/broadcast loads). Identical fmaf order
// to the old dtproj kernel -> bit-identical dt. Eliminates the dtproj
// dispatch, its 12.6 MB write, and dt reads in p1+p3 (~38 MB traffic).
// lane = channel d (coalesced xc/xz streams), 16 n-states in registers,
// L split into 32 chunks of 32 rows (recurrence linear in h).
// Phase1: per chunk, P = prod(dA), F = h(end | h_start=0)   per (d,n)
// Phase2: h_in(c) = P(c-1)*h_in(c-1) + F(c-1)               (serial, tiny)
// Phase3: re-scan chunk seeded with h_in; y = sum_n h*C + D*u, SiLU(z) gate.
// Depth-1 prefetch on per-lane streams; over-reads land in scratch (valid).
// ---------------------------------------------------------------------------
__device__ __forceinline__ float dt_row(const float4* __restrict__ xr4,
                                        const bf16x8* wd, float bias) {
  float s = bias;
#pragma unroll
  for (int q = 0; q < 6; q++) {
    bf16x8 w = wd[q];
    float4 va = xr4[2 * q], vb = xr4[2 * q + 1];
    s = fmaf(va.x, (float)w[0], s); s = fmaf(va.y, (float)w[1], s);
    s = fmaf(va.z, (float)w[2], s); s = fmaf(va.w, (float)w[3], s);
    s = fmaf(vb.x, (float)w[4], s); s = fmaf(vb.y, (float)w[5], s);
    s = fmaf(vb.z, (float)w[6], s); s = fmaf(vb.w, (float)w[7], s);
  }
  return (s > 20.f) ? s : log1pf(__expf(s));
}

__global__ __launch_bounds__(64) void scan_p1(const bf16_t* __restrict__ xc,
                                              const float* __restrict__ xdbl,
                                              const bf16_t* __restrict__ A_log,
                                              const bf16_t* __restrict__ dtw,
                                              const bf16_t* __restrict__ dtb,
                                              float* __restrict__ P,
                                              float* __restrict__ F) {
  int wg = blockIdx.x;                 // 0..1535
  int dgrp = wg % SCAN_NDG, c2 = wg / SCAN_NDG;   // c2 = b*32+c
  int b = c2 >> 5, c = c2 & 31;
  int d = dgrp * 64 + threadIdx.x;
  int r0 = b * LSEQ + c * SCAN_RPC;

  float Adn[16];
  {
    bf16x8 a0 = *(const bf16x8*)(A_log + (size_t)d * 16);
    bf16x8 a1 = *(const bf16x8*)(A_log + (size_t)d * 16 + 8);
#pragma unroll
    for (int n = 0; n < 8; n++) { Adn[n] = -__expf((float)a0[n]); Adn[n + 8] = -__expf((float)a1[n]); }
  }
  bf16x8 wd[6];
#pragma unroll
  for (int q = 0; q < 6; q++) wd[q] = *(const bf16x8*)(dtw + (size_t)d * DT_RANK + q * 8);
  float bias = (float)dtb[d];

  float h[16], p[16];
#pragma unroll
  for (int n = 0; n < 16; n++) { h[n] = 0.f; p[n] = 1.f; }

  float uv = (float)xc[(size_t)r0 * D_INNER + d];

  for (int i = 0; i < SCAN_RPC; i++) {
    size_t r = (size_t)r0 + i;
    float un = (float)xc[(r + 1) * D_INNER + d];    // depth-1 prefetch (over-read OK)
    const float4* xr4 = (const float4*)(xdbl + r * 80);
    float dtv = dt_row(xr4, wd, bias);
    float dtu = dtv * uv;
#pragma unroll
    for (int g = 0; g < 4; g++) {
      float4 Bq = xr4[12 + g];
      float bq[4] = {Bq.x, Bq.y, Bq.z, Bq.w};
#pragma unroll
      for (int j = 0; j < 4; j++) {
        int n = g * 4 + j;
        float dA = __expf(dtv * Adn[n]);
        h[n] = fmaf(dA, h[n], dtu * bq[j]);
        p[n] *= dA;
      }
    }
    uv = un;
  }

  size_t o = (size_t)c2 * SCAN_STRIDE + (size_t)d * 16;
#pragma unroll
  for (int q = 0; q < 4; q++) {
    *(float4*)(P + o + q * 4) = *(float4*)&p[q * 4];
    *(float4*)(F + o + q * 4) = *(float4*)&h[q * 4];
  }
}

__global__ __launch_bounds__(256) void scan_p2(const float* __restrict__ P,
                                               const float* __restrict__ F,
                                               float* __restrict__ Hin) {
  int gid = blockIdx.x * 256 + threadIdx.x;   // < 49152 = 2*24576
  if (gid >= 2 * SCAN_STRIDE) return;
  int b = gid / SCAN_STRIDE, j = gid - b * SCAN_STRIDE;
  float pP[SCAN_C], pF[SCAN_C];
#pragma unroll
  for (int c = 0; c < SCAN_C; c++) {
    size_t o = (size_t)(b * SCAN_C + c) * SCAN_STRIDE + j;
    pP[c] = P[o]; pF[c] = F[o];
  }
  float h = 0.f;
#pragma unroll
  for (int c = 0; c < SCAN_C; c++) {
    size_t o = (size_t)(b * SCAN_C + c) * SCAN_STRIDE + j;
    Hin[o] = h;
    h = fmaf(pP[c], h, pF[c]);
  }
}

__global__ __launch_bounds__(64) void scan_p3(const bf16_t* __restrict__ xc,
                                              const float* __restrict__ xdbl,
                                              const float* __restrict__ xz,
                                              const bf16_t* __restrict__ A_log,
                                              const bf16_t* __restrict__ dtw,
                                              const bf16_t* __restrict__ dtb,
                                              const bf16_t* __restrict__ Dp,
                                              const float* __restrict__ Hin,
                                              bf16_t* __restrict__ yg) {
  int wg = blockIdx.x;
  int dgrp = wg % SCAN_NDG, c2 = wg / SCAN_NDG;
  int b = c2 >> 5, c = c2 & 31;
  int d = dgrp * 64 + threadIdx.x;
  int r0 = b * LSEQ + c * SCAN_RPC;

  float Adn[16];
  {
    bf16x8 a0 = *(const bf16x8*)(A_log + (size_t)d * 16);
    bf16x8 a1 = *(const bf16x8*)(A_log + (size_t)d * 16 + 8);
#pragma unroll
    for (int n = 0; n < 8; n++) { Adn[n] = -__expf((float)a0[n]); Adn[n + 8] = -__expf((float)a1[n]); }
  }
  bf16x8 wd[6];
#pragma unroll
  for (int q = 0; q < 6; q++) wd[q] = *(const bf16x8*)(dtw + (size_t)d * DT_RANK + q * 8);
  float bias = (float)dtb[d];
  float Dd = (float)Dp[d];

  float h[16];
  {
    size_t o = (size_t)c2 * SCAN_STRIDE + (size_t)d * 16;
#pragma unroll
    for (int q = 0; q < 4; q++) *(float4*)&h[q * 4] = *(const float4*)(Hin + o + q * 4);
  }

  float uv = (float)xc[(size_t)r0 * D_INNER + d];
  float zv = xz[(size_t)r0 * (2 * D_INNER) + D_INNER + d];

  for (int i = 0; i < SCAN_RPC; i++) {
    size_t r = (size_t)r0 + i;
    float un = (float)xc[(r + 1) * D_INNER + d];                    // prefetch
    float zn = xz[(r + 1) * (2 * D_INNER) + D_INNER + d];           // prefetch
    const float4* xr4 = (const float4*)(xdbl + r * 80);
    float dtv = dt_row(xr4, wd, bias);
    float dtu = dtv * uv;
    float y = 0.f;
#pragma unroll
    for (int g = 0; g < 4; g++) {
      float4 Bq = xr4[12 + g];
      float4 Cq = xr4[16 + g];
      float bq[4] = {Bq.x, Bq.y, Bq.z, Bq.w};
      float cq[4] = {Cq.x, Cq.y, Cq.z, Cq.w};
#pragma unroll
      for (int j = 0; j < 4; j++) {
        int n = g * 4 + j;
        float dA = __expf(dtv * Adn[n]);
        h[n] = fmaf(dA, h[n], dtu * bq[j]);
        y = fmaf(h[n], cq[j], y);
      }
    }
    float sil = zv / (1.f + __expf(-zv));
    yg[r * D_INNER + d] = (bf16_t)((y + Dd * uv) * sil);
    uv = un; zv = zn;
  }
}

// ---------------------------------------------------------------------------
// LayerNorm over 768, bf16 out (logits A-operand).
// ---------------------------------------------------------------------------
__global__ __launch_bounds__(256) void ln_kernel(const float* __restrict__ h,
                                                 const bf16_t* __restrict__ w,
                                                 const bf16_t* __restrict__ b,
                                                 bf16_t* __restrict__ out) {
  __shared__ float s1[4], s2[4];
  int row = blockIdx.x;
  int tid = threadIdx.x, lane = tid & 63, wave = tid >> 6;
  const float* hr = h + (size_t)row * D_MODEL;
  float a = 0.f, a2 = 0.f;
  for (int i = tid; i < D_MODEL; i += 256) {
    float v = hr[i];
    a += v; a2 += v * v;
  }
#pragma unroll
  for (int m = 32; m >= 1; m >>= 1) {
    a += __shfl_xor(a, m, 64);
    a2 += __shfl_xor(a2, m, 64);
  }
  if (lane == 0) { s1[wave] = a; s2[wave] = a2; }
  __syncthreads();
  float sum = s1[0] + s1[1] + s1[2] + s1[3];
  float sum2 = s2[0] + s2[1] + s2[2] + s2[3];
  float mu = sum / D_MODEL;
  float var = sum2 / D_MODEL - mu * mu;
  float inv = rsqrtf(var + 1e-5f);
  for (int i = tid; i < D_MODEL; i += 256)
    out[(size_t)row * D_MODEL + i] = (bf16_t)((hr[i] - mu) * inv * (float)w[i] + (float)b[i]);
}

// ---------------------------------------------------------------------------
extern "C" void kernel_launch(void* const* d_in, const int* in_sizes, int n_in,
                              void* d_out, int out_size, void* d_ws, size_t ws_size,
                              hipStream_t stream) {
  const int* x = (const int*)d_in[0];
  const void* emb = d_in[1];
  float* out = (float*)d_out;                    // OUTPUT IS FP32 (reference dtype)

  // --- scratch inside d_out (dead before the final logits GEMM writes it) ---
  char* ob = (char*)d_out;
  float* h = (float*)(ob + 0);                   //  6,291,456 B
  bf16_t* hb = (bf16_t*)(ob + 6291456);          //  3,145,728 B
  float* xz = (float*)(ob + 9437184);            // 25,165,824 B
  bf16_t* xc = (bf16_t*)(ob + 34603008);         //  6,291,456 B
  float* xdbl = (float*)(ob + 40894464);         //    655,360 B
  /* (41.5-54.1 MB region free; dt buffer eliminated) */
  bf16_t* yg = (bf16_t*)(ob + 54132736);         //  6,291,456 B
  bf16_t* wk = (bf16_t*)(ob + 60424192);         // 15,086,592 B canonical bf16 weights
  bf16_t* c_xpwp = (bf16_t*)(ob + 75510784);     //    786,432 B padded x_proj W (2x128x1536)
  float* scanP = (float*)(ob + 76297216);        //  6,291,456 B
  float* scanF = (float*)(ob + 82588672);        //  6,291,456 B
  float* scanH = (float*)(ob + 88880128);        //  6,291,456 B (ends 95.2 MB < 262 MB)
  // --- d_ws: data that must survive the logits GEMM + dtype flag ---
  bf16_t* lno = (bf16_t*)d_ws;                   //  3,145,728 B
  int* flag = (int*)((char*)d_ws + 3145728);
  bf16_t* embb = (bf16_t*)((char*)d_ws + 3145744); // 49,152,000 B (optional)
  int bigws = ws_size >= (size_t)3145744 + 49152000u;

  // canonical weight layout (element offsets into wk)
  bf16_t* c_inw  = wk + 0;          // 2*3072*768 = 4,718,592
  bf16_t* c_cw   = wk + 4718592;    // 12,288
  bf16_t* c_cb   = wk + 4730880;    // 3,072
  bf16_t* c_dtw  = wk + 4979712;    // 147,456
  bf16_t* c_dtb  = wk + 5127168;    // 3,072
  bf16_t* c_alog = wk + 5130240;    // 49,152
  bf16_t* c_dp   = wk + 5179392;    // 3,072
  bf16_t* c_outw = wk + 5182464;    // 2,359,296
  bf16_t* c_lnw  = wk + 7541760;    // 768
  bf16_t* c_lnb  = wk + 7542528;    // 768

  if (!bigws)
    detect_kernel<<<1, 64, 0, stream>>>((const unsigned int*)d_in[11], flag);

  CvtSrcs srcs;
  for (int k = 0; k < 11; k++) srcs.p[k] = d_in[k + 2];
  // fused preprocessing: 12,581,376 threads -> 49,146 blocks
  fused_pre<<<49146, 256, 0, stream>>>(srcs, x, emb, wk, c_xpwp, embb, h, hb, bigws);

  for (int i = 0; i < 2; i++) {
    // in_proj: grid (16 m-blocks, 24 n-blocks), XCD-chunked (384%8==0)
    gemm_bt<<<dim3(16, 3072 / 128), 256, 0, stream>>>(
        hb, c_inw + (size_t)i * 2 * D_INNER * D_MODEL, NROWS, 2 * D_INNER, D_MODEL,
        0, xz, nullptr, nullptr, nullptr, 2);
    conv_silu<<<(NROWS * D_INNER + 255) / 256, 256, 0, stream>>>(
        xz, c_cw + (size_t)i * D_INNER * 4, c_cb + (size_t)i * D_INNER, xc);
    // x_proj as MFMA GEMM: N=128 (padded W), writes xdbl (stride 80, col<80)
    gemm_bt<<<dim3(1, NROWS / 128), 256, 0, stream>>>(
        xc, c_xpwp + (size_t)i * 128 * D_INNER, NROWS, 128, D_INNER,
        3, xdbl, nullptr, nullptr, nullptr, 0);
    scan_p1<<<2 * SCAN_C * SCAN_NDG, 64, 0, stream>>>(
        xc, xdbl, c_alog + (size_t)i * D_INNER * D_STATE,
        c_dtw + (size_t)i * D_INNER * DT_RANK, c_dtb + (size_t)i * D_INNER,
        scanP, scanF);
    scan_p2<<<(2 * SCAN_STRIDE + 255) / 256, 256, 0, stream>>>(scanP, scanF, scanH);
    scan_p3<<<2 * SCAN_C * SCAN_NDG, 64, 0, stream>>>(
        xc, xdbl, xz, c_alog + (size_t)i * D_INNER * D_STATE,
        c_dtw + (size_t)i * D_INNER * DT_RANK, c_dtb + (size_t)i * D_INNER,
        c_dp + (size_t)i * D_INNER, scanH, yg);
    // out_proj: grid (16 m-blocks, 6 n-blocks), XCD-chunked (96%8==0)
    gemm_bt<<<dim3(16, D_MODEL / 128), 256, 0, stream>>>(
        yg, c_outw + (size_t)i * D_MODEL * D_INNER, NROWS, D_MODEL, D_INNER,
        1, h, hb, h, nullptr, 2);
  }

  ln_kernel<<<NROWS, 256, 0, stream>>>(h, c_lnw, c_lnb, lno);

  // logits (fp32) = lno @ emb^T. grid (16 m-blocks, 250 n-blocks),
  // XCD-chunked (4000%8==0): all 16 sharers of a B panel on one XCD L2.
  if (bigws)
    gemm_bt<<<dim3(16, 32000 / 128), 256, 0, stream>>>(
        lno, embb, NROWS, 32000, D_MODEL, 2, out, nullptr, nullptr, nullptr, 2);
  else
    gemm_bt<<<dim3(16, 32000 / 128), 256, 0, stream>>>(
        lno, emb, NROWS, 32000, D_MODEL, 2, out, nullptr, nullptr, flag, 2);
}